// Round 4
// baseline (668.876 us; speedup 1.0000x reference)
//
#include <hip/hip_runtime.h>
#include <hip/hip_bf16.h>
#include <math.h>

#define B_ 4
#define S_ 1024
#define D_ 1024
#define H_ 16
#define DK_ 64

typedef short bf16x8 __attribute__((ext_vector_type(8)));
typedef float f32x4 __attribute__((ext_vector_type(4)));

#define MFMA(a, b, c) __builtin_amdgcn_mfma_f32_16x16x32_bf16(a, b, c, 0, 0, 0)

// async global->LDS, 16B per lane. LDS dest = wave-uniform base + lane*16.
#define GLDS(gp, lp)                                                        \
    __builtin_amdgcn_global_load_lds(                                       \
        (const __attribute__((address_space(1))) void*)(const void*)(gp),   \
        (__attribute__((address_space(3))) void*)(void*)(lp), 16, 0, 0)

static __device__ __forceinline__ unsigned short f2bf(float f) {
    __hip_bfloat16 h = __float2bfloat16(f);
    return *reinterpret_cast<unsigned short*>(&h);
}

// ---------------------------------------------------------------------------
// fused f32->bf16 converts
// ---------------------------------------------------------------------------
__global__ __launch_bounds__(256) void cvt3(
    const float* __restrict__ a, const float* __restrict__ b, const float* __restrict__ c,
    unsigned short* __restrict__ oa, unsigned short* __restrict__ ob, unsigned short* __restrict__ oc)
{
    int bx = blockIdx.x;
    int which = bx >> 12;
    const float* in = which == 0 ? a : which == 1 ? b : c;
    unsigned short* out = which == 0 ? oa : which == 1 ? ob : oc;
    int i = (bx & 4095) * 256 + threadIdx.x;
    float4 v = ((const float4*)in)[i];
    ushort4 o;
    o.x = f2bf(v.x); o.y = f2bf(v.y); o.z = f2bf(v.z); o.w = f2bf(v.w);
    ((ushort4*)out)[i] = o;
}

__global__ __launch_bounds__(256) void cvt4(
    const float* __restrict__ a, const float* __restrict__ b,
    const float* __restrict__ c, const float* __restrict__ d,
    unsigned short* __restrict__ oa, unsigned short* __restrict__ ob,
    unsigned short* __restrict__ oc, unsigned short* __restrict__ od)
{
    int bx = blockIdx.x;
    int which = bx >> 10;
    const float* in = which == 0 ? a : which == 1 ? b : which == 2 ? c : d;
    unsigned short* out = which == 0 ? oa : which == 1 ? ob : which == 2 ? oc : od;
    int i = (bx & 1023) * 256 + threadIdx.x;
    float4 v = ((const float4*)in)[i];
    ushort4 o;
    o.x = f2bf(v.x); o.y = f2bf(v.y); o.z = f2bf(v.z); o.w = f2bf(v.w);
    ((ushort4*)out)[i] = o;
}

// ---------------------------------------------------------------------------
// m97-shape bf16 MFMA GEMM: C[4096,1024] = X @ W^T + bvec. Tile 128x128,
// BK=32, 4 waves of 64x64. z-fused QKV.
// mode 0: Q-proj -> bf16, *0.125, zero masked rows
// mode 1: K-proj -> bf16 row-major
// mode 2: V-proj -> bf16 transposed [(b*1024+n)][s]
// mode 3: O-proj -> f32 row-major
// ---------------------------------------------------------------------------
__global__ __launch_bounds__(256, 2) void gemm128(
    const unsigned short* __restrict__ X0, const unsigned short* __restrict__ X1,
    const unsigned short* __restrict__ X2,
    const unsigned short* __restrict__ W0, const unsigned short* __restrict__ W1,
    const unsigned short* __restrict__ W2,
    const float* __restrict__ bv0, const float* __restrict__ bv1,
    const float* __restrict__ bv2,
    void* __restrict__ Y0, void* __restrict__ Y1, void* __restrict__ Y2,
    const int* __restrict__ mask, int mode_ovr)
{
    __shared__ unsigned short As[128 * 32];
    __shared__ unsigned short Bs[128 * 32];

    const int z = blockIdx.z;
    const unsigned short* X = z == 0 ? X0 : z == 1 ? X1 : X2;
    const unsigned short* W = z == 0 ? W0 : z == 1 ? W1 : W2;
    const float* bvec = z == 0 ? bv0 : z == 1 ? bv1 : bv2;
    void* Yv = z == 0 ? Y0 : z == 1 ? Y1 : Y2;
    const int mode = mode_ovr >= 0 ? mode_ovr : z;

    const int t = threadIdx.x;
    const int w = t >> 6, l = t & 63;
    const int lane16 = l & 15, quad = l >> 4;
    const int m0 = blockIdx.y * 128, n0 = blockIdx.x * 128;
    const int wr = w >> 1, wc = w & 1;

    const int srow = w * 16 + (l >> 2);
    const unsigned short* agp = X + (size_t)(m0 + srow) * 1024 + (l & 3) * 8;
    const unsigned short* bgp = W + (size_t)(n0 + srow) * 1024 + (l & 3) * 8;
    unsigned short* alp = As + w * 512 + l * 8;
    unsigned short* blp = Bs + w * 512 + l * 8;

    f32x4 zero = {0.f, 0.f, 0.f, 0.f};
    f32x4 acc[4][4];
    #pragma unroll
    for (int i = 0; i < 4; ++i)
        #pragma unroll
        for (int j = 0; j < 4; ++j) acc[i][j] = zero;

    for (int kt = 0; kt < 1024; kt += 32) {
        GLDS(agp + kt, alp);
        GLDS(agp + kt + 64 * 1024, alp + 2048);
        GLDS(bgp + kt, blp);
        GLDS(bgp + kt + 64 * 1024, blp + 2048);
        __syncthreads();

        bf16x8 af[4], bfv[4];
        #pragma unroll
        for (int i = 0; i < 4; ++i)
            af[i] = *(const bf16x8*)(As + (wr * 64 + i * 16 + lane16) * 32 + quad * 8);
        #pragma unroll
        for (int j = 0; j < 4; ++j)
            bfv[j] = *(const bf16x8*)(Bs + (wc * 64 + j * 16 + lane16) * 32 + quad * 8);

        #pragma unroll
        for (int i = 0; i < 4; ++i)
            #pragma unroll
            for (int j = 0; j < 4; ++j)
                acc[i][j] = MFMA(af[i], bfv[j], acc[i][j]);
        __syncthreads();
    }

    float bvl[4];
    #pragma unroll
    for (int j = 0; j < 4; ++j) bvl[j] = bvec[n0 + wc * 64 + j * 16 + lane16];

    if (mode == 2) {
        const int bb = m0 >> 10;
        const int sb = (m0 & 1023) + wr * 64;
        #pragma unroll
        for (int i = 0; i < 4; ++i) {
            #pragma unroll
            for (int j = 0; j < 4; ++j) {
                int n = n0 + wc * 64 + j * 16 + lane16;
                ushort4 pk;
                pk.x = f2bf(acc[i][j][0] + bvl[j]);
                pk.y = f2bf(acc[i][j][1] + bvl[j]);
                pk.z = f2bf(acc[i][j][2] + bvl[j]);
                pk.w = f2bf(acc[i][j][3] + bvl[j]);
                int s = sb + i * 16 + quad * 4;
                *(ushort4*)((unsigned short*)Yv + ((size_t)(bb * 1024 + n)) * 1024 + s) = pk;
            }
        }
    } else if (mode == 3) {
        float* Y = (float*)Yv;
        #pragma unroll
        for (int i = 0; i < 4; ++i)
            #pragma unroll
            for (int j = 0; j < 4; ++j) {
                int n = n0 + wc * 64 + j * 16 + lane16;
                #pragma unroll
                for (int r = 0; r < 4; ++r) {
                    size_t m = m0 + wr * 64 + i * 16 + quad * 4 + r;
                    Y[m * 1024 + n] = acc[i][j][r] + bvl[j];
                }
            }
    } else {
        unsigned short* Y = (unsigned short*)Yv;
        #pragma unroll
        for (int i = 0; i < 4; ++i) {
            int mrow[4];
            #pragma unroll
            for (int r = 0; r < 4; ++r)
                mrow[r] = (mode == 0) ? mask[m0 + wr * 64 + i * 16 + quad * 4 + r] : 1;
            #pragma unroll
            for (int j = 0; j < 4; ++j) {
                int n = n0 + wc * 64 + j * 16 + lane16;
                #pragma unroll
                for (int r = 0; r < 4; ++r) {
                    size_t m = m0 + wr * 64 + i * 16 + quad * 4 + r;
                    float val = acc[i][j][r] + bvl[j];
                    if (mode == 0) val = mrow[r] ? val * 0.125f : 0.f;
                    Y[m * 1024 + n] = f2bf(val);
                }
            }
        }
    }
}

// ---------------------------------------------------------------------------
// All-heads MFMA flash attention. Block = (b, 16 q rows) x ALL 16 heads.
// 512 threads / 8 waves; wave w owns heads 2w, 2w+1.
// Per iter: stage K[32 keys][1024 d] (xor-swizzled) + V^T[1024 hd][32 keys],
// read raw f32 bias coalesced (float2 = both heads of this wave, nontemporal),
// mask+scale inline, online softmax, P->LDS->A-frag, PV.
// Bias line [q][k][16h] fully consumed across the 8 waves -> no over-fetch.
// ---------------------------------------------------------------------------
__global__ __launch_bounds__(512, 2) void attn_mfma2(
    const unsigned short* __restrict__ Qp, const unsigned short* __restrict__ Kp,
    const unsigned short* __restrict__ VpT, const float* __restrict__ bias,
    const int* __restrict__ mask, unsigned short* __restrict__ Xp)
{
    __shared__ unsigned short Ks[32 * 1024];   // [key][dim], 16B granules xor row&7
    __shared__ unsigned short Vs[1024 * 32];   // [h*64+dk][key]
    __shared__ unsigned short Ps[8][16 * 72];  // per-wave P scratch (reused per head)

    const int t = threadIdx.x;
    const int w = t >> 6, l = t & 63;
    const int lane16 = l & 15, quad = l >> 4;

    const int bid = blockIdx.x;
    const int b = bid & 3, qt = bid >> 2;   // blocks of same b alternate 2 XCDs
    const int q0 = qt * 16;
    const int h0 = w * 2;

    // Q fragments (pre-scaled by 0.125 in projection)
    bf16x8 qf[2][2];
    #pragma unroll
    for (int hh = 0; hh < 2; ++hh)
        #pragma unroll
        for (int c = 0; c < 2; ++c)
            qf[hh][c] = *(const bf16x8*)(Qp + (size_t)(b * 1024 + q0 + lane16) * 1024
                                         + (h0 + hh) * 64 + c * 32 + quad * 8);

    int mq[4];
    #pragma unroll
    for (int r = 0; r < 4; ++r) mq[r] = mask[b * 1024 + q0 + quad * 4 + r];

    const float* brp[4];
    #pragma unroll
    for (int r = 0; r < 4; ++r)
        brp[r] = bias + ((size_t)(b * 1024 + q0 + quad * 4 + r) * 1024 + lane16) * 16 + h0;

    f32x4 zero = {0.f, 0.f, 0.f, 0.f};
    f32x4 o[2][4];
    float m_i[2][4], l_i[2][4];
    #pragma unroll
    for (int hh = 0; hh < 2; ++hh)
        #pragma unroll
        for (int r = 0; r < 4; ++r) {
            m_i[hh][r] = -1e30f; l_i[hh][r] = 0.f;
            o[hh][r] = zero;
        }

    for (int kt = 0; kt < 32; ++kt) {
        const int k0 = kt * 32;

        // stage K: 8 waves x 4 rows, 2 half-rows each (granule-xor by row&7)
        #pragma unroll
        for (int i = 0; i < 8; ++i) {
            int row = w * 4 + (i >> 1), half = i & 1;
            GLDS(Kp + (size_t)(b * 1024 + k0 + row) * 1024
                    + (half * 64 + (l ^ (row & 7))) * 8,
                 Ks + row * 1024 + half * 512);
        }
        // stage V^T: 1024 rows x 64B chunks; wave w rows w*128..+127
        #pragma unroll
        for (int i = 0; i < 8; ++i) {
            int vr0 = w * 128 + i * 16;
            GLDS(VpT + (size_t)(b * 1024 + vr0 + (l >> 2)) * 1024 + k0 + (l & 3) * 8,
                 Vs + vr0 * 32);
        }

        // bias (both heads: float2, nontemporal to protect K/V in L2) + key mask
        int mk[2];
        double bvd[2][4];
        #pragma unroll
        for (int j = 0; j < 2; ++j) {
            mk[j] = mask[b * 1024 + k0 + j * 16 + lane16];
            #pragma unroll
            for (int r = 0; r < 4; ++r)
                bvd[j][r] = __builtin_nontemporal_load(
                    (const double*)(brp[r] + (size_t)(k0 + j * 16) * 16));
        }
        __syncthreads();

        // S = Q K^T for 2 heads
        f32x4 s[2][2];
        #pragma unroll
        for (int hh = 0; hh < 2; ++hh)
            #pragma unroll
            for (int j = 0; j < 2; ++j) {
                s[hh][j] = zero;
                #pragma unroll
                for (int c = 0; c < 2; ++c) {
                    bf16x8 kf = *(const bf16x8*)(Ks + (j * 16 + lane16) * 1024
                        + ((h0 + hh) * 8 + ((c * 4 + quad) ^ (lane16 & 7))) * 8);
                    s[hh][j] = MFMA(qf[hh][c], kf, s[hh][j]);
                }
            }

        #pragma unroll
        for (int hh = 0; hh < 2; ++hh) {
            // bias + mask + scale (Q pre-scaled; bias needs *0.125)
            float sc[2][4];
            #pragma unroll
            for (int j = 0; j < 2; ++j)
                #pragma unroll
                for (int r = 0; r < 4; ++r) {
                    union { double d; float2 f; } u; u.d = bvd[j][r];
                    float bv = hh ? u.f.y : u.f.x;
                    float v = fmaf(bv, 0.125f, s[hh][j][r]);
                    sc[j][r] = (mq[r] && mk[j]) ? v : -1e9f;
                }

            // online softmax (row = quad*4+r spread over 16 lanes)
            float p[2][4];
            #pragma unroll
            for (int r = 0; r < 4; ++r) {
                float mx = fmaxf(sc[0][r], sc[1][r]);
                #pragma unroll
                for (int d = 1; d < 16; d <<= 1) mx = fmaxf(mx, __shfl_xor(mx, d, 64));
                float mnew = fmaxf(m_i[hh][r], mx);
                float alpha = __expf(m_i[hh][r] - mnew);
                m_i[hh][r] = mnew;
                p[0][r] = __expf(sc[0][r] - mnew);
                p[1][r] = __expf(sc[1][r] - mnew);
                float sum = p[0][r] + p[1][r];
                #pragma unroll
                for (int d = 1; d < 16; d <<= 1) sum += __shfl_xor(sum, d, 64);
                l_i[hh][r] = l_i[hh][r] * alpha + sum;
                #pragma unroll
                for (int jd = 0; jd < 4; ++jd) o[hh][jd][r] *= alpha;
            }

            // P: C-layout -> LDS -> A-layout (intra-wave, buffer reused per head)
            #pragma unroll
            for (int j = 0; j < 2; ++j)
                #pragma unroll
                for (int r = 0; r < 4; ++r)
                    Ps[w][(quad * 4 + r) * 72 + j * 16 + lane16] = f2bf(p[j][r]);
            asm volatile("" ::: "memory");
            bf16x8 pf = *(const bf16x8*)(&Ps[w][lane16 * 72 + quad * 8]);
            asm volatile("" ::: "memory");

            // O += P V (K=32 exactly one MFMA per dk-tile)
            #pragma unroll
            for (int jd = 0; jd < 4; ++jd) {
                bf16x8 vf = *(const bf16x8*)(Vs + ((h0 + hh) * 64 + jd * 16 + lane16) * 32
                                             + quad * 8);
                o[hh][jd] = MFMA(pf, vf, o[hh][jd]);
            }
        }
        __syncthreads();
    }

    #pragma unroll
    for (int hh = 0; hh < 2; ++hh) {
        float inv[4];
        #pragma unroll
        for (int r = 0; r < 4; ++r) inv[r] = 1.0f / l_i[hh][r];
        #pragma unroll
        for (int jd = 0; jd < 4; ++jd)
            #pragma unroll
            for (int r = 0; r < 4; ++r)
                Xp[(size_t)(b * 1024 + q0 + quad * 4 + r) * 1024
                   + (h0 + hh) * 64 + jd * 16 + lane16] = f2bf(o[hh][jd][r] * inv[r]);
    }
}

// ---------------------------------------------------------------------------
extern "C" void kernel_launch(void* const* d_in, const int* in_sizes, int n_in,
                              void* d_out, int out_size, void* d_ws, size_t ws_size,
                              hipStream_t stream)
{
    const float* query = (const float*)d_in[0];
    const float* key   = (const float*)d_in[1];
    const float* value = (const float*)d_in[2];
    const float* abias = (const float*)d_in[3];
    const int*   mask  = (const int*)d_in[4];
    const float* Wq = (const float*)d_in[5];
    const float* bq = (const float*)d_in[6];
    const float* Wk = (const float*)d_in[7];
    const float* bk = (const float*)d_in[8];
    const float* Wv = (const float*)d_in[9];
    const float* bv = (const float*)d_in[10];
    const float* Wo = (const float*)d_in[11];
    const float* bo = (const float*)d_in[12];
    float* out = (float*)d_out;

    const size_t T = (size_t)B_ * S_ * D_;   // 4 Mi
    const size_t WSZ = (size_t)D_ * D_;      // 1 Mi
    unsigned short* p = (unsigned short*)d_ws;
    unsigned short* qb  = p;  p += T;
    unsigned short* kb  = p;  p += T;
    unsigned short* vb  = p;  p += T;
    unsigned short* wqb = p;  p += WSZ;
    unsigned short* wkb = p;  p += WSZ;
    unsigned short* wvb = p;  p += WSZ;
    unsigned short* wob = p;  p += WSZ;
    unsigned short* Qpj = p;  p += T;
    unsigned short* Kpj = p;  p += T;
    unsigned short* VpT = p;  p += T;
    unsigned short* Xpj = p;  p += T;

    cvt3<<<dim3(3 * 4096), 256, 0, stream>>>(query, key, value, qb, kb, vb);
    cvt4<<<dim3(4 * 1024), 256, 0, stream>>>(Wq, Wk, Wv, Wo, wqb, wkb, wvb, wob);

    // fused Q/K/V projections
    gemm128<<<dim3(8, 32, 3), 256, 0, stream>>>(
        qb, kb, vb, wqb, wkb, wvb, bq, bk, bv,
        (void*)Qpj, (void*)Kpj, (void*)VpT, mask, -1);

    // attention: 256 blocks x 512 threads, raw f32 bias
    attn_mfma2<<<dim3(256), 512, 0, stream>>>(Qpj, Kpj, VpT, abias, mask, Xpj);

    // output projection (f32 out)
    gemm128<<<dim3(8, 32, 1), 256, 0, stream>>>(
        Xpj, Xpj, Xpj, wob, wob, wob, bo, bo, bo,
        (void*)out, (void*)out, (void*)out, mask, 3);
}